// Round 2
// baseline (1095.341 us; speedup 1.0000x reference)
//
#include <hip/hip_runtime.h>
#include <math.h>

// GumbelVQTokenizer: n=131072, d=128, num_code=512
// out = [quantized (n*128) | encodings (n*512) | indices-as-float (n)]  fp32
//
// Round 2: occupancy + latency-decoupling rework of the R1 MFMA kernel.
//   - A-fragments built fully in registers (direct global x loads + shfl_xor norm
//     reduce + 3-term bf16 split). xs[] LDS removed -> 36 KB LDS -> 4 blocks/CU.
//   - noise prefetched coalesced at kernel top into registers, parked into the
//     logits LDS buffer (wave-private columns, no barrier), ds_read in G1 epilogue.
//   - softmax re-mapped to 16-chunk stride per lane (bank-conflict-free).
//   - G1 B-frags streamed from L2 in 2-ks chunks (lower register pressure under
//     __launch_bounds__(256,4)).

#define N_TOK 131072
#define DIM   128
#define NC    512
#define RB    16
#define NBLK  (N_TOK / RB)        // 8192
#define EPSF  1e-6f
#define LP    516                 // logits row stride (f32)

typedef unsigned short u16;
typedef __attribute__((ext_vector_type(8))) short bf16x8;   // 8 bf16 (4 VGPRs)
typedef __attribute__((ext_vector_type(4))) float f32x4;

__device__ __forceinline__ u16 f2bf(float f) {              // f32 -> bf16 RNE
    unsigned u = __float_as_uint(f);
    u += 0x7fffu + ((u >> 16) & 1u);
    return (u16)(u >> 16);
}
__device__ __forceinline__ float bf2f(u16 h) {
    return __uint_as_float(((unsigned)h) << 16);
}
__device__ __forceinline__ unsigned pack2(float e) {        // e -> lo:bf16(e), hi:bf16(residual)
    u16 h0 = f2bf(e);
    u16 h1 = f2bf(e - bf2f(h0));
    return (unsigned)h0 | ((unsigned)h1 << 16);
}

__global__ __launch_bounds__(256) void prep_cb(const float* __restrict__ cb,
    u16* __restrict__ c0, u16* __restrict__ c1, u16* __restrict__ c2,
    u16* __restrict__ t0, u16* __restrict__ t1)
{
    int idx = blockIdx.x * 256 + threadIdx.x;   // 0 .. 512*128-1
    int c = idx >> 7, k = idx & 127;
    float v = cb[idx];
    u16 b0 = f2bf(v);  float r1 = v - bf2f(b0);
    u16 b1 = f2bf(r1); float r2 = r1 - bf2f(b1);
    u16 b2 = f2bf(r2);
    c0[idx] = b0; c1[idx] = b1; c2[idx] = b2;
    t0[k * NC + c] = b0; t1[k * NC + c] = b1;
}

__global__ __launch_bounds__(256, 4) void vq_main(
    const float* __restrict__ x, const float* __restrict__ mask,
    const u16* __restrict__ cb0, const u16* __restrict__ cb1, const u16* __restrict__ cb2,
    const u16* __restrict__ cbT0, const u16* __restrict__ cbT1,
    const float* __restrict__ noise,
    float* __restrict__ out_q, float* __restrict__ out_e, float* __restrict__ out_i)
{
    __shared__ __align__(16) float L[RB][LP];        // 33024 B; logits f32, later packed 2xbf16
    __shared__ float red[RB][33];                    //  2112 B
    __shared__ float wbv[4][RB]; __shared__ int wbi[4][RB]; __shared__ float wm[4][RB];
    __shared__ float Mrow[RB];  __shared__ float SInv[RB];

    const int tid  = threadIdx.x;
    const int row0 = blockIdx.x * RB;
    const int w    = tid >> 6;        // wave 0..3
    const int lane = tid & 63;
    const int lr   = lane & 15;       // A/B frag: row/col-in-tile ; D frag: col
    const int lg   = lane >> 4;       // k-group

    // ---------------- issue x loads (oldest in vmcnt queue -> P0 doesn't wait on noise) ----
    float4 xa[4], xb[4];
    {
        const float4* xp = reinterpret_cast<const float4*>(x + (size_t)(row0 + lr) * DIM);
#pragma unroll
        for (int ks = 0; ks < 4; ++ks) {
            xa[ks] = xp[ks * 8 + lg * 2];
            xb[ks] = xp[ks * 8 + lg * 2 + 1];
        }
    }
    const float msk = mask[row0 + lr];

    // ---------------- issue noise prefetch (wave-private 128-col slice, 16 rows) ----------
    // lane l: row = 2i + (l>>5), 16B chunk = l&31  -> two 512B coalesced segments per load
    float4 nbuf[8];
    const int nrh = lane >> 5;
    const int ncc = lane & 31;
#pragma unroll
    for (int i = 0; i < 8; ++i) {
        int r = 2 * i + nrh;
        nbuf[i] = *reinterpret_cast<const float4*>(
            noise + (size_t)(row0 + r) * NC + w * 128 + ncc * 4);
    }

    // ---------------- P0: nudge, row-norm (shfl reduce), 3-term bf16 split, all in regs ----
    bf16x8 A0[4], A1[4], A2[4];
    {
        float nd = (1.0f - msk) * EPSF;
        float ss = 0.f;
#pragma unroll
        for (int ks = 0; ks < 4; ++ks) {
            xa[ks].x += nd; xa[ks].y += nd; xa[ks].z += nd; xa[ks].w += nd;
            xb[ks].x += nd; xb[ks].y += nd; xb[ks].z += nd; xb[ks].w += nd;
            ss += xa[ks].x*xa[ks].x + xa[ks].y*xa[ks].y + xa[ks].z*xa[ks].z + xa[ks].w*xa[ks].w;
            ss += xb[ks].x*xb[ks].x + xb[ks].y*xb[ks].y + xb[ks].z*xb[ks].z + xb[ks].w*xb[ks].w;
        }
        // lanes {lr, lr+16, lr+32, lr+48} hold the 4 k-quarters of row lr
        ss += __shfl_xor(ss, 16);
        ss += __shfl_xor(ss, 32);
        float inv = 1.0f / fmaxf(sqrtf(ss), EPSF);
#pragma unroll
        for (int ks = 0; ks < 4; ++ks) {
            float e[8] = { xa[ks].x*inv, xa[ks].y*inv, xa[ks].z*inv, xa[ks].w*inv,
                           xb[ks].x*inv, xb[ks].y*inv, xb[ks].z*inv, xb[ks].w*inv };
#pragma unroll
            for (int j = 0; j < 8; ++j) {
                u16 b0 = f2bf(e[j]);  float r1 = e[j] - bf2f(b0);
                u16 b1 = f2bf(r1);
                u16 b2 = f2bf(r1 - bf2f(b1));
                A0[ks][j] = (short)b0; A1[ks][j] = (short)b1; A2[ks][j] = (short)b2;
            }
        }
    }

    // ---------------- park noise into L (wave-private columns; no barrier needed) --------
#pragma unroll
    for (int i = 0; i < 8; ++i) {
        int r = 2 * i + nrh;
        *reinterpret_cast<float4*>(&L[r][w * 128 + ncc * 4]) = nbuf[i];
    }

    // ---------------- G1: ab = xn . cb^T via 6-term split-bf16 MFMA ----------------
    float bv[4], mx[4]; int bi[4];
#pragma unroll
    for (int r = 0; r < 4; ++r) { bv[r] = -1e30f; mx[r] = -1e30f; bi[r] = 0; }

    const int blofs = lr * DIM + lg * 8;            // lane part of B-frag index

#pragma unroll
    for (int it = 0; it < 8; ++it) {
        const int c0 = (w * 8 + it) * 16;
        const u16* p0 = cb0 + c0 * DIM + blofs;
        const u16* p1 = cb1 + c0 * DIM + blofs;
        const u16* p2 = cb2 + c0 * DIM + blofs;

        f32x4 ac0 = {0.f,0.f,0.f,0.f}, ac1 = {0.f,0.f,0.f,0.f}, ac2 = {0.f,0.f,0.f,0.f};
#pragma unroll
        for (int kk = 0; kk < 2; ++kk) {            // 2-ks chunks: lower live B regs
            bf16x8 B0[2], B1[2], B2[2];
#pragma unroll
            for (int s = 0; s < 2; ++s) {
                int ks = kk * 2 + s;
                B0[s] = *reinterpret_cast<const bf16x8*>(p0 + ks * 32);
                B1[s] = *reinterpret_cast<const bf16x8*>(p1 + ks * 32);
                B2[s] = *reinterpret_cast<const bf16x8*>(p2 + ks * 32);
            }
#pragma unroll
            for (int s = 0; s < 2; ++s) {
                int ks = kk * 2 + s;
                ac0 = __builtin_amdgcn_mfma_f32_16x16x32_bf16(A0[ks], B0[s], ac0, 0,0,0);
                ac0 = __builtin_amdgcn_mfma_f32_16x16x32_bf16(A1[ks], B1[s], ac0, 0,0,0);
                ac1 = __builtin_amdgcn_mfma_f32_16x16x32_bf16(A0[ks], B1[s], ac1, 0,0,0);
                ac1 = __builtin_amdgcn_mfma_f32_16x16x32_bf16(A1[ks], B0[s], ac1, 0,0,0);
                ac2 = __builtin_amdgcn_mfma_f32_16x16x32_bf16(A0[ks], B2[s], ac2, 0,0,0);
                ac2 = __builtin_amdgcn_mfma_f32_16x16x32_bf16(A2[ks], B0[s], ac2, 0,0,0);
            }
        }
        f32x4 ab = (ac0 + ac1) + ac2;

#pragma unroll
        for (int r = 0; r < 4; ++r) {
            float a = ab[r];
            if (a > bv[r]) { bv[r] = a; bi[r] = c0 + lr; }    // strict > keeps lowest code
            float nz = L[lg * 4 + r][c0 + lr];                // prefetched noise (LDS)
            float l = fmaf(2.f, a, nz);
            mx[r] = fmaxf(mx[r], l);
            L[lg * 4 + r][c0 + lr] = l;                       // D-frag row=(lane>>4)*4+r, col=lane&15
        }
    }

    // 16-lane (code dim) shuffle reduce, then cross-wave LDS reduce
#pragma unroll
    for (int off = 1; off <= 8; off <<= 1) {
#pragma unroll
        for (int r = 0; r < 4; ++r) {
            float ov = __shfl_xor(bv[r], off);
            int   oi = __shfl_xor(bi[r], off);
            if (ov > bv[r] || (ov == bv[r] && oi < bi[r])) { bv[r] = ov; bi[r] = oi; }
            mx[r] = fmaxf(mx[r], __shfl_xor(mx[r], off));
        }
    }
    if (lr == 0) {
#pragma unroll
        for (int r = 0; r < 4; ++r) {
            int row = lg * 4 + r;
            wbv[w][row] = bv[r]; wbi[w][row] = bi[r]; wm[w][row] = mx[r];
        }
    }
    __syncthreads();
    if (tid < RB) {
        float B = -1e30f; int I = 0; float M = -1e30f;
#pragma unroll
        for (int ww = 0; ww < 4; ++ww) {
            float ov = wbv[ww][tid]; int oi = wbi[ww][tid];
            if (ov > B || (ov == B && oi < I)) { B = ov; I = oi; }
            M = fmaxf(M, wm[ww][tid]);
        }
        out_i[row0 + tid] = (float)I;
        Mrow[tid] = M;
    }
    __syncthreads();

    // ---------------- softmax: exp in place (packed 2xbf16), 16-chunk stride (no conflicts)
    {
        int r = tid >> 4, p = tid & 15;
        float M = Mrow[r];
        float lsum = 0.f;
#pragma unroll
        for (int j = 0; j < 8; ++j) {
            float4* lp = reinterpret_cast<float4*>(&L[r][(p + 16 * j) * 4]);
            float4 t = *lp;
            float e0 = __expf(t.x - M), e1 = __expf(t.y - M);
            float e2 = __expf(t.z - M), e3 = __expf(t.w - M);
            lsum += (e0 + e1) + (e2 + e3);
            uint4 u;
            u.x = pack2(e0); u.y = pack2(e1); u.z = pack2(e2); u.w = pack2(e3);
            *reinterpret_cast<uint4*>(lp) = u;
        }
        red[r][p] = lsum;
    }
    __syncthreads();
    if (tid < RB) {
        float s = 0.f;
#pragma unroll
        for (int j = 0; j < 16; ++j) s += red[tid][j];
        SInv[tid] = 1.0f / s;
    }
    __syncthreads();

    // ---------------- encodings write (reconstruct f32, coalesced float4) ----------------
    {
        float4* eout = reinterpret_cast<float4*>(out_e + (size_t)row0 * NC);
#pragma unroll
        for (int i = 0; i < 8; ++i) {
            int g = tid + 256 * i;          // 0..2047 float4 over 16x512
            int row = g >> 7, c4 = g & 127;
            uint4 u = *reinterpret_cast<const uint4*>(&L[row][c4 * 4]);
            float inv = SInv[row];
            float4 o;
            o.x = (__uint_as_float(u.x << 16) + __uint_as_float(u.x & 0xffff0000u)) * inv;
            o.y = (__uint_as_float(u.y << 16) + __uint_as_float(u.y & 0xffff0000u)) * inv;
            o.z = (__uint_as_float(u.z << 16) + __uint_as_float(u.z & 0xffff0000u)) * inv;
            o.w = (__uint_as_float(u.w << 16) + __uint_as_float(u.w & 0xffff0000u)) * inv;
            eout[g] = o;
        }
    }

    // ---------------- G2: quantized = (E . cb) * SInv via 3-term split-bf16 MFMA ----------
    {
        f32x4 aA[2], aB[2], aC[2];
#pragma unroll
        for (int t2 = 0; t2 < 2; ++t2) {
            aA[t2] = (f32x4){0.f,0.f,0.f,0.f};
            aB[t2] = (f32x4){0.f,0.f,0.f,0.f};
            aC[t2] = (f32x4){0.f,0.f,0.f,0.f};
        }
        const int tb = lr * NC + lg * 8;    // lane part of cbT frag index
#pragma unroll 4
        for (int ks = 0; ks < 16; ++ks) {
            const unsigned* Lr = reinterpret_cast<const unsigned*>(&L[lr][ks * 32 + lg * 8]);
            uint4 q0 = *reinterpret_cast<const uint4*>(Lr);
            uint4 q1 = *reinterpret_cast<const uint4*>(Lr + 4);
            uint4 d0, d1;                   // unpack: E0 = lo16 halves, E1 = hi16 halves
            d0.x = __builtin_amdgcn_perm(q0.y, q0.x, 0x05040100u);
            d0.y = __builtin_amdgcn_perm(q0.w, q0.z, 0x05040100u);
            d0.z = __builtin_amdgcn_perm(q1.y, q1.x, 0x05040100u);
            d0.w = __builtin_amdgcn_perm(q1.w, q1.z, 0x05040100u);
            d1.x = __builtin_amdgcn_perm(q0.y, q0.x, 0x07060302u);
            d1.y = __builtin_amdgcn_perm(q0.w, q0.z, 0x07060302u);
            d1.z = __builtin_amdgcn_perm(q1.y, q1.x, 0x07060302u);
            d1.w = __builtin_amdgcn_perm(q1.w, q1.z, 0x07060302u);
            bf16x8 e0 = __builtin_bit_cast(bf16x8, d0);
            bf16x8 e1 = __builtin_bit_cast(bf16x8, d1);
#pragma unroll
            for (int t2 = 0; t2 < 2; ++t2) {
                const int dt = w * 2 + t2;
                bf16x8 c0f = *reinterpret_cast<const bf16x8*>(cbT0 + dt * 16 * NC + ks * 32 + tb);
                bf16x8 c1f = *reinterpret_cast<const bf16x8*>(cbT1 + dt * 16 * NC + ks * 32 + tb);
                aA[t2] = __builtin_amdgcn_mfma_f32_16x16x32_bf16(e0, c0f, aA[t2], 0,0,0);
                aB[t2] = __builtin_amdgcn_mfma_f32_16x16x32_bf16(e0, c1f, aB[t2], 0,0,0);
                aC[t2] = __builtin_amdgcn_mfma_f32_16x16x32_bf16(e1, c0f, aC[t2], 0,0,0);
            }
        }
#pragma unroll
        for (int t2 = 0; t2 < 2; ++t2) {
            f32x4 qv = (aA[t2] + aB[t2]) + aC[t2];
            const int dcol = (w * 2 + t2) * 16 + lr;
#pragma unroll
            for (int r = 0; r < 4; ++r) {
                int row = lg * 4 + r;
                out_q[(size_t)(row0 + row) * DIM + dcol] = qv[r] * SInv[row];
            }
        }
    }
}

extern "C" void kernel_launch(void* const* d_in, const int* in_sizes, int n_in,
                              void* d_out, int out_size, void* d_ws, size_t ws_size,
                              hipStream_t stream)
{
    const float* x     = (const float*)d_in[0];
    const float* mask  = (const float*)d_in[1];
    const float* cb    = (const float*)d_in[2];
    const float* noise = (const float*)d_in[3];

    float* out_q = (float*)d_out;                       // n*128
    float* out_e = out_q + (size_t)N_TOK * DIM;         // n*512
    float* out_i = out_e + (size_t)N_TOK * NC;          // n (indices as float)

    u16* cb0  = (u16*)d_ws;                             // 5 x 128 KB = 640 KB workspace
    u16* cb1  = cb0 + 65536;
    u16* cb2  = cb1 + 65536;
    u16* cbT0 = cb2 + 65536;
    u16* cbT1 = cbT0 + 65536;

    hipLaunchKernelGGL(prep_cb, dim3(256), dim3(256), 0, stream, cb, cb0, cb1, cb2, cbT0, cbT1);
    hipLaunchKernelGGL(vq_main, dim3(NBLK), dim3(256), 0, stream,
                       x, mask, cb0, cb1, cb2, cbT0, cbT1, noise, out_q, out_e, out_i);
}

// Round 3
// 1036.435 us; speedup vs baseline: 1.0568x; 1.0568x over previous
//
#include <hip/hip_runtime.h>
#include <math.h>

// GumbelVQTokenizer: n=131072, d=128, num_code=512
// out = [quantized (n*128) | encodings (n*512) | indices-as-float (n)]  fp32
//
// Round 3: fix R2's register-spill pathology (WRITE_SIZE 328->615MB at VGPR cap 64).
//   - noise removed from G1 entirely: G1 stores 2*ab to LDS; softmax phase reads
//     noise straight from global (block slice is contiguous 32KB, fully coalesced)
//     and does row-max/sum via shfl within the 16-lane row group. Kills the 32-reg
//     noise prefetch, Mrow/red/wm arrays, and one barrier.
//   - G1 tracks argmax(ab) only (no logit-max): -4 regs, fewer shfls.
//   - peak live set ~100 regs -> fits the 128-reg budget of __launch_bounds__(256,4)
//     with no scratch. LDS ~33.6KB -> 4 blocks/CU.

#define N_TOK 131072
#define DIM   128
#define NC    512
#define RB    16
#define NBLK  (N_TOK / RB)        // 8192
#define EPSF  1e-6f
#define LP    516                 // logits row stride (f32)

typedef unsigned short u16;
typedef __attribute__((ext_vector_type(8))) short bf16x8;   // 8 bf16 (4 VGPRs)
typedef __attribute__((ext_vector_type(4))) float f32x4;

__device__ __forceinline__ u16 f2bf(float f) {              // f32 -> bf16 RNE
    unsigned u = __float_as_uint(f);
    u += 0x7fffu + ((u >> 16) & 1u);
    return (u16)(u >> 16);
}
__device__ __forceinline__ float bf2f(u16 h) {
    return __uint_as_float(((unsigned)h) << 16);
}
__device__ __forceinline__ unsigned pack2(float e) {        // e -> lo:bf16(e), hi:bf16(residual)
    u16 h0 = f2bf(e);
    u16 h1 = f2bf(e - bf2f(h0));
    return (unsigned)h0 | ((unsigned)h1 << 16);
}

__global__ __launch_bounds__(256) void prep_cb(const float* __restrict__ cb,
    u16* __restrict__ c0, u16* __restrict__ c1, u16* __restrict__ c2,
    u16* __restrict__ t0, u16* __restrict__ t1)
{
    int idx = blockIdx.x * 256 + threadIdx.x;   // 0 .. 512*128-1
    int c = idx >> 7, k = idx & 127;
    float v = cb[idx];
    u16 b0 = f2bf(v);  float r1 = v - bf2f(b0);
    u16 b1 = f2bf(r1); float r2 = r1 - bf2f(b1);
    u16 b2 = f2bf(r2);
    c0[idx] = b0; c1[idx] = b1; c2[idx] = b2;
    t0[k * NC + c] = b0; t1[k * NC + c] = b1;
}

__global__ __launch_bounds__(256, 4) void vq_main(
    const float* __restrict__ x, const float* __restrict__ mask,
    const u16* __restrict__ cb0, const u16* __restrict__ cb1, const u16* __restrict__ cb2,
    const u16* __restrict__ cbT0, const u16* __restrict__ cbT1,
    const float* __restrict__ noise,
    float* __restrict__ out_q, float* __restrict__ out_e, float* __restrict__ out_i)
{
    __shared__ __align__(16) float L[RB][LP];        // 33024 B; 2*ab f32, later packed 2xbf16 exp
    __shared__ float wbv[4][RB]; __shared__ int wbi[4][RB];
    __shared__ float SInv[RB];

    const int tid  = threadIdx.x;
    const int row0 = blockIdx.x * RB;
    const int w    = tid >> 6;        // wave 0..3
    const int lane = tid & 63;
    const int lr   = lane & 15;       // A/B frag: row/col-in-tile ; D frag: col
    const int lg   = lane >> 4;       // k-group

    // ---------------- x loads ----------------
    float4 xa[4], xb[4];
    {
        const float4* xp = reinterpret_cast<const float4*>(x + (size_t)(row0 + lr) * DIM);
#pragma unroll
        for (int ks = 0; ks < 4; ++ks) {
            xa[ks] = xp[ks * 8 + lg * 2];
            xb[ks] = xp[ks * 8 + lg * 2 + 1];
        }
    }
    const float msk = mask[row0 + lr];

    // ---------------- P0: nudge, row-norm (shfl reduce), 3-term bf16 split, in regs ----
    bf16x8 A0[4], A1[4], A2[4];
    {
        float nd = (1.0f - msk) * EPSF;
        float ss = 0.f;
#pragma unroll
        for (int ks = 0; ks < 4; ++ks) {
            xa[ks].x += nd; xa[ks].y += nd; xa[ks].z += nd; xa[ks].w += nd;
            xb[ks].x += nd; xb[ks].y += nd; xb[ks].z += nd; xb[ks].w += nd;
            ss += xa[ks].x*xa[ks].x + xa[ks].y*xa[ks].y + xa[ks].z*xa[ks].z + xa[ks].w*xa[ks].w;
            ss += xb[ks].x*xb[ks].x + xb[ks].y*xb[ks].y + xb[ks].z*xb[ks].z + xb[ks].w*xb[ks].w;
        }
        // lanes {lr, lr+16, lr+32, lr+48} hold the 4 k-quarters of row lr
        ss += __shfl_xor(ss, 16);
        ss += __shfl_xor(ss, 32);
        float inv = 1.0f / fmaxf(sqrtf(ss), EPSF);
#pragma unroll
        for (int ks = 0; ks < 4; ++ks) {
            float e[8] = { xa[ks].x*inv, xa[ks].y*inv, xa[ks].z*inv, xa[ks].w*inv,
                           xb[ks].x*inv, xb[ks].y*inv, xb[ks].z*inv, xb[ks].w*inv };
#pragma unroll
            for (int j = 0; j < 8; ++j) {
                u16 b0 = f2bf(e[j]);  float r1 = e[j] - bf2f(b0);
                u16 b1 = f2bf(r1);
                u16 b2 = f2bf(r1 - bf2f(b1));
                A0[ks][j] = (short)b0; A1[ks][j] = (short)b1; A2[ks][j] = (short)b2;
            }
        }
    }

    // ---------------- G1: ab = xn . cb^T via 6-term split-bf16 MFMA (noise-free) --------
    float bv[4]; int bi[4];
#pragma unroll
    for (int r = 0; r < 4; ++r) { bv[r] = -1e30f; bi[r] = 0; }

    const int blofs = lr * DIM + lg * 8;            // lane part of B-frag index

#pragma unroll
    for (int it = 0; it < 8; ++it) {
        const int c0 = (w * 8 + it) * 16;
        const u16* p0 = cb0 + c0 * DIM + blofs;
        const u16* p1 = cb1 + c0 * DIM + blofs;
        const u16* p2 = cb2 + c0 * DIM + blofs;

        f32x4 ac0 = {0.f,0.f,0.f,0.f}, ac1 = {0.f,0.f,0.f,0.f}, ac2 = {0.f,0.f,0.f,0.f};
#pragma unroll
        for (int kk = 0; kk < 2; ++kk) {            // 2-ks chunks: lower live B regs
            bf16x8 B0[2], B1[2], B2[2];
#pragma unroll
            for (int s = 0; s < 2; ++s) {
                int ks = kk * 2 + s;
                B0[s] = *reinterpret_cast<const bf16x8*>(p0 + ks * 32);
                B1[s] = *reinterpret_cast<const bf16x8*>(p1 + ks * 32);
                B2[s] = *reinterpret_cast<const bf16x8*>(p2 + ks * 32);
            }
#pragma unroll
            for (int s = 0; s < 2; ++s) {
                int ks = kk * 2 + s;
                ac0 = __builtin_amdgcn_mfma_f32_16x16x32_bf16(A0[ks], B0[s], ac0, 0,0,0);
                ac0 = __builtin_amdgcn_mfma_f32_16x16x32_bf16(A1[ks], B1[s], ac0, 0,0,0);
                ac1 = __builtin_amdgcn_mfma_f32_16x16x32_bf16(A0[ks], B1[s], ac1, 0,0,0);
                ac1 = __builtin_amdgcn_mfma_f32_16x16x32_bf16(A1[ks], B0[s], ac1, 0,0,0);
                ac2 = __builtin_amdgcn_mfma_f32_16x16x32_bf16(A0[ks], B2[s], ac2, 0,0,0);
                ac2 = __builtin_amdgcn_mfma_f32_16x16x32_bf16(A2[ks], B0[s], ac2, 0,0,0);
            }
        }
        f32x4 ab = (ac0 + ac1) + ac2;

#pragma unroll
        for (int r = 0; r < 4; ++r) {
            float a = ab[r];
            if (a > bv[r]) { bv[r] = a; bi[r] = c0 + lr; }    // strict > keeps lowest code
            L[lg * 4 + r][c0 + lr] = 2.0f * a;                // D-frag row=(lane>>4)*4+r, col=lane&15
        }
    }

    // 16-lane (code dim) shuffle argmax reduce, then cross-wave LDS reduce
#pragma unroll
    for (int off = 1; off <= 8; off <<= 1) {
#pragma unroll
        for (int r = 0; r < 4; ++r) {
            float ov = __shfl_xor(bv[r], off);
            int   oi = __shfl_xor(bi[r], off);
            if (ov > bv[r] || (ov == bv[r] && oi < bi[r])) { bv[r] = ov; bi[r] = oi; }
        }
    }
    if (lr == 0) {
#pragma unroll
        for (int r = 0; r < 4; ++r) {
            int row = lg * 4 + r;
            wbv[w][row] = bv[r]; wbi[w][row] = bi[r];
        }
    }
    __syncthreads();
    if (tid < RB) {
        float B = -1e30f; int I = 0;
#pragma unroll
        for (int ww = 0; ww < 4; ++ww) {
            float ov = wbv[ww][tid]; int oi = wbi[ww][tid];
            if (ov > B || (ov == B && oi < I)) { B = ov; I = oi; }
        }
        out_i[row0 + tid] = (float)I;
    }

    // ---------------- softmax: l = 2ab + noise (noise straight from HBM, coalesced),
    //                  row max+sum via shfl in 16-lane row groups, pack 2xbf16 in place
    {
        const int r = tid >> 4, p = tid & 15;
        const float* nrow = noise + (size_t)(row0 + r) * NC;
        float4 Nz[8];
#pragma unroll
        for (int j = 0; j < 8; ++j)
            Nz[j] = *reinterpret_cast<const float4*>(nrow + (p + 16 * j) * 4);
        float4 Lv[8];
#pragma unroll
        for (int j = 0; j < 8; ++j) {
            float4 t = *reinterpret_cast<const float4*>(&L[r][(p + 16 * j) * 4]);
            t.x += Nz[j].x; t.y += Nz[j].y; t.z += Nz[j].z; t.w += Nz[j].w;
            Lv[j] = t;
        }
        float m = -1e30f;
#pragma unroll
        for (int j = 0; j < 8; ++j)
            m = fmaxf(m, fmaxf(fmaxf(Lv[j].x, Lv[j].y), fmaxf(Lv[j].z, Lv[j].w)));
#pragma unroll
        for (int off = 1; off <= 8; off <<= 1)
            m = fmaxf(m, __shfl_xor(m, off));
        float s = 0.f;
        uint4 pk[8];
#pragma unroll
        for (int j = 0; j < 8; ++j) {
            float e0 = __expf(Lv[j].x - m), e1 = __expf(Lv[j].y - m);
            float e2 = __expf(Lv[j].z - m), e3 = __expf(Lv[j].w - m);
            s += (e0 + e1) + (e2 + e3);
            pk[j].x = pack2(e0); pk[j].y = pack2(e1);
            pk[j].z = pack2(e2); pk[j].w = pack2(e3);
        }
#pragma unroll
        for (int off = 1; off <= 8; off <<= 1)
            s += __shfl_xor(s, off);
        if (p == 0) SInv[r] = 1.0f / s;
#pragma unroll
        for (int j = 0; j < 8; ++j)
            *reinterpret_cast<uint4*>(&L[r][(p + 16 * j) * 4]) = pk[j];
    }
    __syncthreads();

    // ---------------- encodings write (reconstruct f32, coalesced float4) ----------------
    {
        float4* eout = reinterpret_cast<float4*>(out_e + (size_t)row0 * NC);
#pragma unroll
        for (int i = 0; i < 8; ++i) {
            int g = tid + 256 * i;          // 0..2047 float4 over 16x512
            int row = g >> 7, c4 = g & 127;
            uint4 u = *reinterpret_cast<const uint4*>(&L[row][c4 * 4]);
            float inv = SInv[row];
            float4 o;
            o.x = (__uint_as_float(u.x << 16) + __uint_as_float(u.x & 0xffff0000u)) * inv;
            o.y = (__uint_as_float(u.y << 16) + __uint_as_float(u.y & 0xffff0000u)) * inv;
            o.z = (__uint_as_float(u.z << 16) + __uint_as_float(u.z & 0xffff0000u)) * inv;
            o.w = (__uint_as_float(u.w << 16) + __uint_as_float(u.w & 0xffff0000u)) * inv;
            eout[g] = o;
        }
    }

    // ---------------- G2: quantized = (E . cb) * SInv via 3-term split-bf16 MFMA ----------
    {
        f32x4 aA[2], aB[2], aC[2];
#pragma unroll
        for (int t2 = 0; t2 < 2; ++t2) {
            aA[t2] = (f32x4){0.f,0.f,0.f,0.f};
            aB[t2] = (f32x4){0.f,0.f,0.f,0.f};
            aC[t2] = (f32x4){0.f,0.f,0.f,0.f};
        }
        const int tb = lr * NC + lg * 8;    // lane part of cbT frag index
#pragma unroll 4
        for (int ks = 0; ks < 16; ++ks) {
            const unsigned* Lr = reinterpret_cast<const unsigned*>(&L[lr][ks * 32 + lg * 8]);
            uint4 q0 = *reinterpret_cast<const uint4*>(Lr);
            uint4 q1 = *reinterpret_cast<const uint4*>(Lr + 4);
            uint4 d0, d1;                   // unpack: E0 = lo16 halves, E1 = hi16 halves
            d0.x = __builtin_amdgcn_perm(q0.y, q0.x, 0x05040100u);
            d0.y = __builtin_amdgcn_perm(q0.w, q0.z, 0x05040100u);
            d0.z = __builtin_amdgcn_perm(q1.y, q1.x, 0x05040100u);
            d0.w = __builtin_amdgcn_perm(q1.w, q1.z, 0x05040100u);
            d1.x = __builtin_amdgcn_perm(q0.y, q0.x, 0x07060302u);
            d1.y = __builtin_amdgcn_perm(q0.w, q0.z, 0x07060302u);
            d1.z = __builtin_amdgcn_perm(q1.y, q1.x, 0x07060302u);
            d1.w = __builtin_amdgcn_perm(q1.w, q1.z, 0x07060302u);
            bf16x8 e0 = __builtin_bit_cast(bf16x8, d0);
            bf16x8 e1 = __builtin_bit_cast(bf16x8, d1);
#pragma unroll
            for (int t2 = 0; t2 < 2; ++t2) {
                const int dt = w * 2 + t2;
                bf16x8 c0f = *reinterpret_cast<const bf16x8*>(cbT0 + dt * 16 * NC + ks * 32 + tb);
                bf16x8 c1f = *reinterpret_cast<const bf16x8*>(cbT1 + dt * 16 * NC + ks * 32 + tb);
                aA[t2] = __builtin_amdgcn_mfma_f32_16x16x32_bf16(e0, c0f, aA[t2], 0,0,0);
                aB[t2] = __builtin_amdgcn_mfma_f32_16x16x32_bf16(e0, c1f, aB[t2], 0,0,0);
                aC[t2] = __builtin_amdgcn_mfma_f32_16x16x32_bf16(e1, c0f, aC[t2], 0,0,0);
            }
        }
#pragma unroll
        for (int t2 = 0; t2 < 2; ++t2) {
            f32x4 qv = (aA[t2] + aB[t2]) + aC[t2];
            const int dcol = (w * 2 + t2) * 16 + lr;
#pragma unroll
            for (int r = 0; r < 4; ++r) {
                int row = lg * 4 + r;
                out_q[(size_t)(row0 + row) * DIM + dcol] = qv[r] * SInv[row];
            }
        }
    }
}

extern "C" void kernel_launch(void* const* d_in, const int* in_sizes, int n_in,
                              void* d_out, int out_size, void* d_ws, size_t ws_size,
                              hipStream_t stream)
{
    const float* x     = (const float*)d_in[0];
    const float* mask  = (const float*)d_in[1];
    const float* cb    = (const float*)d_in[2];
    const float* noise = (const float*)d_in[3];

    float* out_q = (float*)d_out;                       // n*128
    float* out_e = out_q + (size_t)N_TOK * DIM;         // n*512
    float* out_i = out_e + (size_t)N_TOK * NC;          // n (indices as float)

    u16* cb0  = (u16*)d_ws;                             // 5 x 128 KB = 640 KB workspace
    u16* cb1  = cb0 + 65536;
    u16* cb2  = cb1 + 65536;
    u16* cbT0 = cb2 + 65536;
    u16* cbT1 = cbT0 + 65536;

    hipLaunchKernelGGL(prep_cb, dim3(256), dim3(256), 0, stream, cb, cb0, cb1, cb2, cbT0, cbT1);
    hipLaunchKernelGGL(vq_main, dim3(NBLK), dim3(256), 0, stream,
                       x, mask, cb0, cb1, cb2, cbT0, cbT1, noise, out_q, out_e, out_i);
}

// Round 4
// 1023.343 us; speedup vs baseline: 1.0704x; 1.0128x over previous
//
#include <hip/hip_runtime.h>
#include <math.h>

// GumbelVQTokenizer: n=131072, d=128, num_code=512
// out = [quantized (n*128) | encodings (n*512) | indices-as-float (n)]  fp32
//
// Round 4: register-budget fix. R3 still spilled (~139MB extra WRITE_SIZE) because
// __launch_bounds__(256,4) gives a 128-reg unified budget -> 64 arch VGPRs, below
// G1's ~90-reg live set. Switch to (256,3): 170-reg budget fits the R1-style
// no-spill allocation (~150 total) while keeping 1.5x R1's occupancy (3 blocks/CU).
//   - softmax noise adds streamed (Nz chunk-live, not array-live).
//   - everything else identical to R3.

#define N_TOK 131072
#define DIM   128
#define NC    512
#define RB    16
#define NBLK  (N_TOK / RB)        // 8192
#define EPSF  1e-6f
#define LP    516                 // logits row stride (f32)

typedef unsigned short u16;
typedef __attribute__((ext_vector_type(8))) short bf16x8;   // 8 bf16 (4 VGPRs)
typedef __attribute__((ext_vector_type(4))) float f32x4;

__device__ __forceinline__ u16 f2bf(float f) {              // f32 -> bf16 RNE
    unsigned u = __float_as_uint(f);
    u += 0x7fffu + ((u >> 16) & 1u);
    return (u16)(u >> 16);
}
__device__ __forceinline__ float bf2f(u16 h) {
    return __uint_as_float(((unsigned)h) << 16);
}
__device__ __forceinline__ unsigned pack2(float e) {        // e -> lo:bf16(e), hi:bf16(residual)
    u16 h0 = f2bf(e);
    u16 h1 = f2bf(e - bf2f(h0));
    return (unsigned)h0 | ((unsigned)h1 << 16);
}

__global__ __launch_bounds__(256) void prep_cb(const float* __restrict__ cb,
    u16* __restrict__ c0, u16* __restrict__ c1, u16* __restrict__ c2,
    u16* __restrict__ t0, u16* __restrict__ t1)
{
    int idx = blockIdx.x * 256 + threadIdx.x;   // 0 .. 512*128-1
    int c = idx >> 7, k = idx & 127;
    float v = cb[idx];
    u16 b0 = f2bf(v);  float r1 = v - bf2f(b0);
    u16 b1 = f2bf(r1); float r2 = r1 - bf2f(b1);
    u16 b2 = f2bf(r2);
    c0[idx] = b0; c1[idx] = b1; c2[idx] = b2;
    t0[k * NC + c] = b0; t1[k * NC + c] = b1;
}

__global__ __launch_bounds__(256, 3) void vq_main(
    const float* __restrict__ x, const float* __restrict__ mask,
    const u16* __restrict__ cb0, const u16* __restrict__ cb1, const u16* __restrict__ cb2,
    const u16* __restrict__ cbT0, const u16* __restrict__ cbT1,
    const float* __restrict__ noise,
    float* __restrict__ out_q, float* __restrict__ out_e, float* __restrict__ out_i)
{
    __shared__ __align__(16) float L[RB][LP];        // 33024 B; 2*ab f32, later packed 2xbf16 exp
    __shared__ float wbv[4][RB]; __shared__ int wbi[4][RB];
    __shared__ float SInv[RB];

    const int tid  = threadIdx.x;
    const int row0 = blockIdx.x * RB;
    const int w    = tid >> 6;        // wave 0..3
    const int lane = tid & 63;
    const int lr   = lane & 15;       // A/B frag: row/col-in-tile ; D frag: col
    const int lg   = lane >> 4;       // k-group

    // ---------------- x loads ----------------
    float4 xa[4], xb[4];
    {
        const float4* xp = reinterpret_cast<const float4*>(x + (size_t)(row0 + lr) * DIM);
#pragma unroll
        for (int ks = 0; ks < 4; ++ks) {
            xa[ks] = xp[ks * 8 + lg * 2];
            xb[ks] = xp[ks * 8 + lg * 2 + 1];
        }
    }
    const float msk = mask[row0 + lr];

    // ---------------- P0: nudge, row-norm (shfl reduce), 3-term bf16 split, in regs ----
    bf16x8 A0[4], A1[4], A2[4];
    {
        float nd = (1.0f - msk) * EPSF;
        float ss = 0.f;
#pragma unroll
        for (int ks = 0; ks < 4; ++ks) {
            xa[ks].x += nd; xa[ks].y += nd; xa[ks].z += nd; xa[ks].w += nd;
            xb[ks].x += nd; xb[ks].y += nd; xb[ks].z += nd; xb[ks].w += nd;
            ss += xa[ks].x*xa[ks].x + xa[ks].y*xa[ks].y + xa[ks].z*xa[ks].z + xa[ks].w*xa[ks].w;
            ss += xb[ks].x*xb[ks].x + xb[ks].y*xb[ks].y + xb[ks].z*xb[ks].z + xb[ks].w*xb[ks].w;
        }
        // lanes {lr, lr+16, lr+32, lr+48} hold the 4 k-quarters of row lr
        ss += __shfl_xor(ss, 16);
        ss += __shfl_xor(ss, 32);
        float inv = 1.0f / fmaxf(sqrtf(ss), EPSF);
#pragma unroll
        for (int ks = 0; ks < 4; ++ks) {
            float e[8] = { xa[ks].x*inv, xa[ks].y*inv, xa[ks].z*inv, xa[ks].w*inv,
                           xb[ks].x*inv, xb[ks].y*inv, xb[ks].z*inv, xb[ks].w*inv };
#pragma unroll
            for (int j = 0; j < 8; ++j) {
                u16 b0 = f2bf(e[j]);  float r1 = e[j] - bf2f(b0);
                u16 b1 = f2bf(r1);
                u16 b2 = f2bf(r1 - bf2f(b1));
                A0[ks][j] = (short)b0; A1[ks][j] = (short)b1; A2[ks][j] = (short)b2;
            }
        }
    }

    // ---------------- G1: ab = xn . cb^T via 6-term split-bf16 MFMA (noise-free) --------
    float bv[4]; int bi[4];
#pragma unroll
    for (int r = 0; r < 4; ++r) { bv[r] = -1e30f; bi[r] = 0; }

    const int blofs = lr * DIM + lg * 8;            // lane part of B-frag index

#pragma unroll
    for (int it = 0; it < 8; ++it) {
        const int c0 = (w * 8 + it) * 16;
        const u16* p0 = cb0 + c0 * DIM + blofs;
        const u16* p1 = cb1 + c0 * DIM + blofs;
        const u16* p2 = cb2 + c0 * DIM + blofs;

        f32x4 ac0 = {0.f,0.f,0.f,0.f}, ac1 = {0.f,0.f,0.f,0.f}, ac2 = {0.f,0.f,0.f,0.f};
#pragma unroll
        for (int kk = 0; kk < 2; ++kk) {            // 2-ks chunks: lower live B regs
            bf16x8 B0[2], B1[2], B2[2];
#pragma unroll
            for (int s = 0; s < 2; ++s) {
                int ks = kk * 2 + s;
                B0[s] = *reinterpret_cast<const bf16x8*>(p0 + ks * 32);
                B1[s] = *reinterpret_cast<const bf16x8*>(p1 + ks * 32);
                B2[s] = *reinterpret_cast<const bf16x8*>(p2 + ks * 32);
            }
#pragma unroll
            for (int s = 0; s < 2; ++s) {
                int ks = kk * 2 + s;
                ac0 = __builtin_amdgcn_mfma_f32_16x16x32_bf16(A0[ks], B0[s], ac0, 0,0,0);
                ac0 = __builtin_amdgcn_mfma_f32_16x16x32_bf16(A1[ks], B1[s], ac0, 0,0,0);
                ac1 = __builtin_amdgcn_mfma_f32_16x16x32_bf16(A0[ks], B1[s], ac1, 0,0,0);
                ac1 = __builtin_amdgcn_mfma_f32_16x16x32_bf16(A1[ks], B0[s], ac1, 0,0,0);
                ac2 = __builtin_amdgcn_mfma_f32_16x16x32_bf16(A0[ks], B2[s], ac2, 0,0,0);
                ac2 = __builtin_amdgcn_mfma_f32_16x16x32_bf16(A2[ks], B0[s], ac2, 0,0,0);
            }
        }
        f32x4 ab = (ac0 + ac1) + ac2;

#pragma unroll
        for (int r = 0; r < 4; ++r) {
            float a = ab[r];
            if (a > bv[r]) { bv[r] = a; bi[r] = c0 + lr; }    // strict > keeps lowest code
            L[lg * 4 + r][c0 + lr] = 2.0f * a;                // D-frag row=(lane>>4)*4+r, col=lane&15
        }
    }

    // 16-lane (code dim) shuffle argmax reduce, then cross-wave LDS reduce
#pragma unroll
    for (int off = 1; off <= 8; off <<= 1) {
#pragma unroll
        for (int r = 0; r < 4; ++r) {
            float ov = __shfl_xor(bv[r], off);
            int   oi = __shfl_xor(bi[r], off);
            if (ov > bv[r] || (ov == bv[r] && oi < bi[r])) { bv[r] = ov; bi[r] = oi; }
        }
    }
    if (lr == 0) {
#pragma unroll
        for (int r = 0; r < 4; ++r) {
            int row = lg * 4 + r;
            wbv[w][row] = bv[r]; wbi[w][row] = bi[r];
        }
    }
    __syncthreads();
    if (tid < RB) {
        float B = -1e30f; int I = 0;
#pragma unroll
        for (int ww = 0; ww < 4; ++ww) {
            float ov = wbv[ww][tid]; int oi = wbi[ww][tid];
            if (ov > B || (ov == B && oi < I)) { B = ov; I = oi; }
        }
        out_i[row0 + tid] = (float)I;
    }

    // ---------------- softmax: l = 2ab + noise (noise straight from HBM, coalesced),
    //                  row max+sum via shfl in 16-lane row groups, pack 2xbf16 in place
    {
        const int r = tid >> 4, p = tid & 15;
        const float* nrow = noise + (size_t)(row0 + r) * NC;
        float4 Lv[8];
#pragma unroll
        for (int j = 0; j < 8; ++j) {
            float4 nz = *reinterpret_cast<const float4*>(nrow + (p + 16 * j) * 4);
            float4 t = *reinterpret_cast<const float4*>(&L[r][(p + 16 * j) * 4]);
            t.x += nz.x; t.y += nz.y; t.z += nz.z; t.w += nz.w;
            Lv[j] = t;
        }
        float m = -1e30f;
#pragma unroll
        for (int j = 0; j < 8; ++j)
            m = fmaxf(m, fmaxf(fmaxf(Lv[j].x, Lv[j].y), fmaxf(Lv[j].z, Lv[j].w)));
#pragma unroll
        for (int off = 1; off <= 8; off <<= 1)
            m = fmaxf(m, __shfl_xor(m, off));
        float s = 0.f;
#pragma unroll
        for (int j = 0; j < 8; ++j) {
            float e0 = __expf(Lv[j].x - m), e1 = __expf(Lv[j].y - m);
            float e2 = __expf(Lv[j].z - m), e3 = __expf(Lv[j].w - m);
            s += (e0 + e1) + (e2 + e3);
            uint4 pk;
            pk.x = pack2(e0); pk.y = pack2(e1);
            pk.z = pack2(e2); pk.w = pack2(e3);
            *reinterpret_cast<uint4*>(&L[r][(p + 16 * j) * 4]) = pk;
        }
#pragma unroll
        for (int off = 1; off <= 8; off <<= 1)
            s += __shfl_xor(s, off);
        if (p == 0) SInv[r] = 1.0f / s;
    }
    __syncthreads();

    // ---------------- encodings write (reconstruct f32, coalesced float4) ----------------
    {
        float4* eout = reinterpret_cast<float4*>(out_e + (size_t)row0 * NC);
#pragma unroll
        for (int i = 0; i < 8; ++i) {
            int g = tid + 256 * i;          // 0..2047 float4 over 16x512
            int row = g >> 7, c4 = g & 127;
            uint4 u = *reinterpret_cast<const uint4*>(&L[row][c4 * 4]);
            float inv = SInv[row];
            float4 o;
            o.x = (__uint_as_float(u.x << 16) + __uint_as_float(u.x & 0xffff0000u)) * inv;
            o.y = (__uint_as_float(u.y << 16) + __uint_as_float(u.y & 0xffff0000u)) * inv;
            o.z = (__uint_as_float(u.z << 16) + __uint_as_float(u.z & 0xffff0000u)) * inv;
            o.w = (__uint_as_float(u.w << 16) + __uint_as_float(u.w & 0xffff0000u)) * inv;
            eout[g] = o;
        }
    }

    // ---------------- G2: quantized = (E . cb) * SInv via 3-term split-bf16 MFMA ----------
    {
        f32x4 aA[2], aB[2], aC[2];
#pragma unroll
        for (int t2 = 0; t2 < 2; ++t2) {
            aA[t2] = (f32x4){0.f,0.f,0.f,0.f};
            aB[t2] = (f32x4){0.f,0.f,0.f,0.f};
            aC[t2] = (f32x4){0.f,0.f,0.f,0.f};
        }
        const int tb = lr * NC + lg * 8;    // lane part of cbT frag index
#pragma unroll 4
        for (int ks = 0; ks < 16; ++ks) {
            const unsigned* Lr = reinterpret_cast<const unsigned*>(&L[lr][ks * 32 + lg * 8]);
            uint4 q0 = *reinterpret_cast<const uint4*>(Lr);
            uint4 q1 = *reinterpret_cast<const uint4*>(Lr + 4);
            uint4 d0, d1;                   // unpack: E0 = lo16 halves, E1 = hi16 halves
            d0.x = __builtin_amdgcn_perm(q0.y, q0.x, 0x05040100u);
            d0.y = __builtin_amdgcn_perm(q0.w, q0.z, 0x05040100u);
            d0.z = __builtin_amdgcn_perm(q1.y, q1.x, 0x05040100u);
            d0.w = __builtin_amdgcn_perm(q1.w, q1.z, 0x05040100u);
            d1.x = __builtin_amdgcn_perm(q0.y, q0.x, 0x07060302u);
            d1.y = __builtin_amdgcn_perm(q0.w, q0.z, 0x07060302u);
            d1.z = __builtin_amdgcn_perm(q1.y, q1.x, 0x07060302u);
            d1.w = __builtin_amdgcn_perm(q1.w, q1.z, 0x07060302u);
            bf16x8 e0 = __builtin_bit_cast(bf16x8, d0);
            bf16x8 e1 = __builtin_bit_cast(bf16x8, d1);
#pragma unroll
            for (int t2 = 0; t2 < 2; ++t2) {
                const int dt = w * 2 + t2;
                bf16x8 c0f = *reinterpret_cast<const bf16x8*>(cbT0 + dt * 16 * NC + ks * 32 + tb);
                bf16x8 c1f = *reinterpret_cast<const bf16x8*>(cbT1 + dt * 16 * NC + ks * 32 + tb);
                aA[t2] = __builtin_amdgcn_mfma_f32_16x16x32_bf16(e0, c0f, aA[t2], 0,0,0);
                aB[t2] = __builtin_amdgcn_mfma_f32_16x16x32_bf16(e0, c1f, aB[t2], 0,0,0);
                aC[t2] = __builtin_amdgcn_mfma_f32_16x16x32_bf16(e1, c0f, aC[t2], 0,0,0);
            }
        }
#pragma unroll
        for (int t2 = 0; t2 < 2; ++t2) {
            f32x4 qv = (aA[t2] + aB[t2]) + aC[t2];
            const int dcol = (w * 2 + t2) * 16 + lr;
#pragma unroll
            for (int r = 0; r < 4; ++r) {
                int row = lg * 4 + r;
                out_q[(size_t)(row0 + row) * DIM + dcol] = qv[r] * SInv[row];
            }
        }
    }
}

extern "C" void kernel_launch(void* const* d_in, const int* in_sizes, int n_in,
                              void* d_out, int out_size, void* d_ws, size_t ws_size,
                              hipStream_t stream)
{
    const float* x     = (const float*)d_in[0];
    const float* mask  = (const float*)d_in[1];
    const float* cb    = (const float*)d_in[2];
    const float* noise = (const float*)d_in[3];

    float* out_q = (float*)d_out;                       // n*128
    float* out_e = out_q + (size_t)N_TOK * DIM;         // n*512
    float* out_i = out_e + (size_t)N_TOK * NC;          // n (indices as float)

    u16* cb0  = (u16*)d_ws;                             // 5 x 128 KB = 640 KB workspace
    u16* cb1  = cb0 + 65536;
    u16* cb2  = cb1 + 65536;
    u16* cbT0 = cb2 + 65536;
    u16* cbT1 = cbT0 + 65536;

    hipLaunchKernelGGL(prep_cb, dim3(256), dim3(256), 0, stream, cb, cb0, cb1, cb2, cbT0, cbT1);
    hipLaunchKernelGGL(vq_main, dim3(NBLK), dim3(256), 0, stream,
                       x, mask, cb0, cb1, cb2, cbT0, cbT1, noise, out_q, out_e, out_i);
}

// Round 5
// 665.750 us; speedup vs baseline: 1.6453x; 1.5371x over previous
//
#include <hip/hip_runtime.h>
#include <math.h>

// GumbelVQTokenizer: n=131072, d=128, num_code=512
// out = [quantized (n*128) | encodings (n*512) | indices-as-float (n)]  fp32
//
// Round 5: L2-traffic attack. R1-R4 were pinned at ~680us regardless of occupancy/
// spills -> saturated shared resource = L2 codebook re-streaming (every block read
// the full 640KB split-codebook as scattered 16B/lane requests; 5.2 GB/dispatch).
//   - RB=32: two 16-row groups per block; B-frags loaded once, used for both ->
//     codebook bytes per row halved.
//   - f16 2-term split (h0+h1, 11-bit mantissa) replaces bf16 3-term: 2 streams
//     instead of 3 in G1, and BETTER accuracy (err ~2^-23 vs ~2^-24*3 terms kept).
//     G1 = 4 MFMAs/ks (h0g0 | h0g1+h1g0 | h1g1), G2 = 3 MFMAs (drop h1g1).
//   - fragment-ordered codebook: prep_cb pre-permutes so every B-frag load is one
//     contiguous 1KB wave-load (64 lanes x 16B sequential) instead of 16 scattered
//     cachelines. Total codebook L2 traffic: 2.1 GB coalesced (was 5.2 scattered).
//   - LDS 67KB -> 2 blocks/CU; launch_bounds(256,2) (256-reg budget, no spills).

#define N_TOK 131072
#define DIM   128
#define NC    512
#define RB    32
#define NBLK  (N_TOK / RB)        // 4096
#define EPSF  1e-6f
#define LP    516                 // logits row stride (f32)

typedef unsigned short u16;
typedef _Float16 f16;
typedef __attribute__((ext_vector_type(8))) _Float16 f16x8;  // 8 f16 (4 VGPRs)
typedef __attribute__((ext_vector_type(4))) float f32x4;

__device__ __forceinline__ unsigned pack2h(float e) {       // lo: f16(e), hi: f16(residual)
    f16 h0 = (f16)e;
    f16 h1 = (f16)(e - (float)h0);
    return (unsigned)__builtin_bit_cast(u16, h0) | ((unsigned)__builtin_bit_cast(u16, h1) << 16);
}
__device__ __forceinline__ float h2f(unsigned b) {
    return (float)__builtin_bit_cast(f16, (u16)(b & 0xffffu));
}

// Fragment-ordered f16 2-split codebooks.
// G1 (fb0/fb1): idx -> j=idx&7, lane=(idx>>3)&63, ks=(idx>>9)&3, t=idx>>11
//   holds cb[code=t*16+(lane&15)][dim=(ks<<5)+((lane>>4)<<3)+j]
// G2 (ft0/ft1): idx -> j=idx&7, lane=(idx>>3)&63, ks=(idx>>9)&15, dt=idx>>13
//   holds cb[k=(ks<<5)+((lane>>4)<<3)+j][d=dt*16+(lane&15)]
__global__ __launch_bounds__(256) void prep_cb(const float* __restrict__ cb,
    u16* __restrict__ fb0, u16* __restrict__ fb1,
    u16* __restrict__ ft0, u16* __restrict__ ft1)
{
    int idx = blockIdx.x * 256 + threadIdx.x;   // 0..65535
    {
        int j = idx & 7, lane = (idx >> 3) & 63, ks = (idx >> 9) & 3, t = idx >> 11;
        int code = t * 16 + (lane & 15);
        int dim  = (ks << 5) + ((lane >> 4) << 3) + j;
        float v = cb[code * DIM + dim];
        f16 h0 = (f16)v; f16 h1 = (f16)(v - (float)h0);
        fb0[idx] = __builtin_bit_cast(u16, h0);
        fb1[idx] = __builtin_bit_cast(u16, h1);
    }
    {
        int j = idx & 7, lane = (idx >> 3) & 63, ks = (idx >> 9) & 15, dt = idx >> 13;
        int d = dt * 16 + (lane & 15);
        int k = (ks << 5) + ((lane >> 4) << 3) + j;
        float v = cb[k * DIM + d];
        f16 g0 = (f16)v; f16 g1 = (f16)(v - (float)g0);
        ft0[idx] = __builtin_bit_cast(u16, g0);
        ft1[idx] = __builtin_bit_cast(u16, g1);
    }
}

__global__ __launch_bounds__(256, 2) void vq_main(
    const float* __restrict__ x, const float* __restrict__ mask,
    const u16* __restrict__ fb0, const u16* __restrict__ fb1,
    const u16* __restrict__ ft0, const u16* __restrict__ ft1,
    const float* __restrict__ noise,
    float* __restrict__ out_q, float* __restrict__ out_e, float* __restrict__ out_i)
{
    __shared__ __align__(16) float L[RB][LP];        // 66048 B
    __shared__ float wbv[4][RB]; __shared__ int wbi[4][RB];
    __shared__ float SInv[RB];

    const int tid  = threadIdx.x;
    const int row0 = blockIdx.x * RB;
    const int w    = tid >> 6;        // wave 0..3
    const int lane = tid & 63;
    const int lr   = lane & 15;       // A/B frag row/col-in-tile ; D frag col
    const int lg   = lane >> 4;       // k-group

    // ---------------- P0: per rowgroup: load x, nudge, row-norm (shfl), f16 2-split ----
    f16x8 A0[2][4], A1[2][4];
#pragma unroll
    for (int h = 0; h < 2; ++h) {
        const int row = row0 + h * 16 + lr;
        const float4* xp = reinterpret_cast<const float4*>(x + (size_t)row * DIM);
        float4 xa[4], xb[4];
#pragma unroll
        for (int ks = 0; ks < 4; ++ks) {
            xa[ks] = xp[ks * 8 + lg * 2];
            xb[ks] = xp[ks * 8 + lg * 2 + 1];
        }
        float nd = (1.0f - mask[row]) * EPSF;
        float ss = 0.f;
#pragma unroll
        for (int ks = 0; ks < 4; ++ks) {
            xa[ks].x += nd; xa[ks].y += nd; xa[ks].z += nd; xa[ks].w += nd;
            xb[ks].x += nd; xb[ks].y += nd; xb[ks].z += nd; xb[ks].w += nd;
            ss += xa[ks].x*xa[ks].x + xa[ks].y*xa[ks].y + xa[ks].z*xa[ks].z + xa[ks].w*xa[ks].w;
            ss += xb[ks].x*xb[ks].x + xb[ks].y*xb[ks].y + xb[ks].z*xb[ks].z + xb[ks].w*xb[ks].w;
        }
        // lanes {lr, lr+16, lr+32, lr+48} hold the 4 k-quarters of this row
        ss += __shfl_xor(ss, 16);
        ss += __shfl_xor(ss, 32);
        float inv = 1.0f / fmaxf(sqrtf(ss), EPSF);
#pragma unroll
        for (int ks = 0; ks < 4; ++ks) {
            float e[8] = { xa[ks].x*inv, xa[ks].y*inv, xa[ks].z*inv, xa[ks].w*inv,
                           xb[ks].x*inv, xb[ks].y*inv, xb[ks].z*inv, xb[ks].w*inv };
#pragma unroll
            for (int j = 0; j < 8; ++j) {
                f16 h0 = (f16)e[j];
                f16 h1 = (f16)(e[j] - (float)h0);
                A0[h][ks][j] = h0; A1[h][ks][j] = h1;
            }
        }
    }

    // ---------------- G1: ab = xn . cb^T via f16 4-term split MFMA, both rowgroups ----
    float bv[2][4]; int bi[2][4];
#pragma unroll
    for (int h = 0; h < 2; ++h)
#pragma unroll
        for (int r = 0; r < 4; ++r) { bv[h][r] = -1e30f; bi[h][r] = 0; }

#pragma unroll
    for (int it = 0; it < 8; ++it) {
        const int t = w * 8 + it, c0 = t * 16;
        f32x4 a00[2], a01[2], a11[2];
#pragma unroll
        for (int h = 0; h < 2; ++h) {
            a00[h] = (f32x4){0.f,0.f,0.f,0.f};
            a01[h] = (f32x4){0.f,0.f,0.f,0.f};
            a11[h] = (f32x4){0.f,0.f,0.f,0.f};
        }
#pragma unroll
        for (int ks = 0; ks < 4; ++ks) {
            const int fo = (t * 4 + ks) * 512 + lane * 8;   // contiguous 1KB wave-load
            f16x8 g0 = *reinterpret_cast<const f16x8*>(fb0 + fo);
            f16x8 g1 = *reinterpret_cast<const f16x8*>(fb1 + fo);
#pragma unroll
            for (int h = 0; h < 2; ++h) {
                a00[h] = __builtin_amdgcn_mfma_f32_16x16x32_f16(A0[h][ks], g0, a00[h], 0,0,0);
                a01[h] = __builtin_amdgcn_mfma_f32_16x16x32_f16(A0[h][ks], g1, a01[h], 0,0,0);
                a01[h] = __builtin_amdgcn_mfma_f32_16x16x32_f16(A1[h][ks], g0, a01[h], 0,0,0);
                a11[h] = __builtin_amdgcn_mfma_f32_16x16x32_f16(A1[h][ks], g1, a11[h], 0,0,0);
            }
        }
#pragma unroll
        for (int h = 0; h < 2; ++h) {
            f32x4 ab = (a11[h] + a01[h]) + a00[h];
#pragma unroll
            for (int r = 0; r < 4; ++r) {
                float a = ab[r];
                if (a > bv[h][r]) { bv[h][r] = a; bi[h][r] = c0 + lr; }  // strict >: lowest idx
                L[h * 16 + lg * 4 + r][c0 + lr] = 2.0f * a;
            }
        }
    }

    // 16-lane (code dim) shuffle argmax reduce, then cross-wave LDS reduce
#pragma unroll
    for (int off = 1; off <= 8; off <<= 1) {
#pragma unroll
        for (int h = 0; h < 2; ++h)
#pragma unroll
            for (int r = 0; r < 4; ++r) {
                float ov = __shfl_xor(bv[h][r], off);
                int   oi = __shfl_xor(bi[h][r], off);
                if (ov > bv[h][r] || (ov == bv[h][r] && oi < bi[h][r])) { bv[h][r] = ov; bi[h][r] = oi; }
            }
    }
    if (lr == 0) {
#pragma unroll
        for (int h = 0; h < 2; ++h)
#pragma unroll
            for (int r = 0; r < 4; ++r) {
                int row = h * 16 + lg * 4 + r;
                wbv[w][row] = bv[h][r]; wbi[w][row] = bi[h][r];
            }
    }
    __syncthreads();
    if (tid < RB) {
        float B = -1e30f; int I = 0;
#pragma unroll
        for (int ww = 0; ww < 4; ++ww) {
            float ov = wbv[ww][tid]; int oi = wbi[ww][tid];
            if (ov > B || (ov == B && oi < I)) { B = ov; I = oi; }
        }
        out_i[row0 + tid] = (float)I;
    }

    // ---------------- softmax: two 16-row passes; noise from HBM (prefetched both),
    //                  row max+sum via shfl in 16-lane groups, pack 2xf16 in place ----
    {
        const int rl = tid >> 4, p = tid & 15;
        float4 Nz[2][8];
#pragma unroll
        for (int ph = 0; ph < 2; ++ph) {
            const float* nrow = noise + (size_t)(row0 + ph * 16 + rl) * NC;
#pragma unroll
            for (int j = 0; j < 8; ++j)
                Nz[ph][j] = *reinterpret_cast<const float4*>(nrow + (p + 16 * j) * 4);
        }
#pragma unroll
        for (int ph = 0; ph < 2; ++ph) {
            const int r = ph * 16 + rl;
            float4 Lv[8];
#pragma unroll
            for (int j = 0; j < 8; ++j) {
                float4 tv = *reinterpret_cast<const float4*>(&L[r][(p + 16 * j) * 4]);
                tv.x += Nz[ph][j].x; tv.y += Nz[ph][j].y;
                tv.z += Nz[ph][j].z; tv.w += Nz[ph][j].w;
                Lv[j] = tv;
            }
            float m = -1e30f;
#pragma unroll
            for (int j = 0; j < 8; ++j)
                m = fmaxf(m, fmaxf(fmaxf(Lv[j].x, Lv[j].y), fmaxf(Lv[j].z, Lv[j].w)));
#pragma unroll
            for (int off = 1; off <= 8; off <<= 1)
                m = fmaxf(m, __shfl_xor(m, off));
            float s = 0.f;
#pragma unroll
            for (int j = 0; j < 8; ++j) {
                float e0 = __expf(Lv[j].x - m), e1 = __expf(Lv[j].y - m);
                float e2 = __expf(Lv[j].z - m), e3 = __expf(Lv[j].w - m);
                s += (e0 + e1) + (e2 + e3);
                uint4 pk;
                pk.x = pack2h(e0); pk.y = pack2h(e1);
                pk.z = pack2h(e2); pk.w = pack2h(e3);
                *reinterpret_cast<uint4*>(&L[r][(p + 16 * j) * 4]) = pk;
            }
#pragma unroll
            for (int off = 1; off <= 8; off <<= 1)
                s += __shfl_xor(s, off);
            if (p == 0) SInv[r] = 1.0f / s;
        }
    }
    __syncthreads();

    // ---------------- encodings write (reconstruct f32, coalesced float4) ----------------
    {
        float4* eout = reinterpret_cast<float4*>(out_e + (size_t)row0 * NC);
#pragma unroll
        for (int i = 0; i < 16; ++i) {
            int g = tid + 256 * i;          // 0..4095 float4 over 32x512
            int row = g >> 7, c4 = g & 127;
            uint4 u = *reinterpret_cast<const uint4*>(&L[row][c4 * 4]);
            float inv = SInv[row];
            float4 o;
            o.x = (h2f(u.x) + h2f(u.x >> 16)) * inv;
            o.y = (h2f(u.y) + h2f(u.y >> 16)) * inv;
            o.z = (h2f(u.z) + h2f(u.z >> 16)) * inv;
            o.w = (h2f(u.w) + h2f(u.w >> 16)) * inv;
            eout[g] = o;
        }
    }

    // ---------------- G2: quantized = (E . cb) * SInv via f16 3-term split MFMA ----------
    {
        f32x4 q00[2][2], q01[2][2];     // [t2][h]
#pragma unroll
        for (int t2 = 0; t2 < 2; ++t2)
#pragma unroll
            for (int h = 0; h < 2; ++h) {
                q00[t2][h] = (f32x4){0.f,0.f,0.f,0.f};
                q01[t2][h] = (f32x4){0.f,0.f,0.f,0.f};
            }
#pragma unroll 4
        for (int ks = 0; ks < 16; ++ks) {
            f16x8 e0[2], e1[2];
#pragma unroll
            for (int h = 0; h < 2; ++h) {
                const unsigned* Lr = reinterpret_cast<const unsigned*>(&L[h * 16 + lr][ks * 32 + lg * 8]);
                uint4 a = *reinterpret_cast<const uint4*>(Lr);
                uint4 b = *reinterpret_cast<const uint4*>(Lr + 4);
                uint4 d0, d1;               // d0 = lo16 halves (h0), d1 = hi16 halves (h1)
                d0.x = __builtin_amdgcn_perm(a.y, a.x, 0x05040100u);
                d0.y = __builtin_amdgcn_perm(a.w, a.z, 0x05040100u);
                d0.z = __builtin_amdgcn_perm(b.y, b.x, 0x05040100u);
                d0.w = __builtin_amdgcn_perm(b.w, b.z, 0x05040100u);
                d1.x = __builtin_amdgcn_perm(a.y, a.x, 0x07060302u);
                d1.y = __builtin_amdgcn_perm(a.w, a.z, 0x07060302u);
                d1.z = __builtin_amdgcn_perm(b.y, b.x, 0x07060302u);
                d1.w = __builtin_amdgcn_perm(b.w, b.z, 0x07060302u);
                e0[h] = __builtin_bit_cast(f16x8, d0);
                e1[h] = __builtin_bit_cast(f16x8, d1);
            }
#pragma unroll
            for (int t2 = 0; t2 < 2; ++t2) {
                const int dt = w * 2 + t2;
                const int fo = (dt * 16 + ks) * 512 + lane * 8;   // contiguous 1KB wave-load
                f16x8 c0f = *reinterpret_cast<const f16x8*>(ft0 + fo);
                f16x8 c1f = *reinterpret_cast<const f16x8*>(ft1 + fo);
#pragma unroll
                for (int h = 0; h < 2; ++h) {
                    q00[t2][h] = __builtin_amdgcn_mfma_f32_16x16x32_f16(e0[h], c0f, q00[t2][h], 0,0,0);
                    q01[t2][h] = __builtin_amdgcn_mfma_f32_16x16x32_f16(e0[h], c1f, q01[t2][h], 0,0,0);
                    q01[t2][h] = __builtin_amdgcn_mfma_f32_16x16x32_f16(e1[h], c0f, q01[t2][h], 0,0,0);
                }
            }
        }
#pragma unroll
        for (int t2 = 0; t2 < 2; ++t2) {
            const int dcol = (w * 2 + t2) * 16 + lr;
#pragma unroll
            for (int h = 0; h < 2; ++h) {
                f32x4 qv = q00[t2][h] + q01[t2][h];
#pragma unroll
                for (int r = 0; r < 4; ++r) {
                    int row = h * 16 + lg * 4 + r;
                    out_q[(size_t)(row0 + row) * DIM + dcol] = qv[r] * SInv[row];
                }
            }
        }
    }
}

extern "C" void kernel_launch(void* const* d_in, const int* in_sizes, int n_in,
                              void* d_out, int out_size, void* d_ws, size_t ws_size,
                              hipStream_t stream)
{
    const float* x     = (const float*)d_in[0];
    const float* mask  = (const float*)d_in[1];
    const float* cb    = (const float*)d_in[2];
    const float* noise = (const float*)d_in[3];

    float* out_q = (float*)d_out;                       // n*128
    float* out_e = out_q + (size_t)N_TOK * DIM;         // n*512
    float* out_i = out_e + (size_t)N_TOK * NC;          // n (indices as float)

    u16* fb0 = (u16*)d_ws;                              // 4 x 128 KB = 512 KB workspace
    u16* fb1 = fb0 + 65536;
    u16* ft0 = fb1 + 65536;
    u16* ft1 = ft0 + 65536;

    hipLaunchKernelGGL(prep_cb, dim3(256), dim3(256), 0, stream, cb, fb0, fb1, ft0, ft1);
    hipLaunchKernelGGL(vq_main, dim3(NBLK), dim3(256), 0, stream,
                       x, mask, fb0, fb1, ft0, ft1, noise, out_q, out_e, out_i);
}